// Round 2
// baseline (259.085 us; speedup 1.0000x reference)
//
#include <hip/hip_runtime.h>
#include <cmath>

#define R_LEVELS 16
#define N_TAB    524288u
#define N_MASK   (N_TAB - 1u)
#define PRIME_H  2654435761u
#define H_DIM    32
#define M_PTS    1048576
#define BDIM     64               // buckets per axis
#define NBUCK    (BDIM * BDIM)    // 4096 Morton buckets

struct ResArr { float r[R_LEVELS]; };

__device__ __forceinline__ unsigned bucket_of(float x, float y) {
    unsigned bx = (unsigned)(x * (float)BDIM); if (bx >= BDIM) bx = BDIM - 1;
    unsigned by = (unsigned)(y * (float)BDIM); if (by >= BDIM) by = BDIM - 1;
    unsigned m = 0;
    #pragma unroll
    for (int i = 0; i < 6; ++i)
        m |= (((bx >> i) & 1u) << (2 * i)) | (((by >> i) & 1u) << (2 * i + 1));
    return m;
}

__global__ __launch_bounds__(256) void hist_k(const float2* __restrict__ coords,
                                              unsigned* __restrict__ counts) {
    const int p = blockIdx.x * blockDim.x + threadIdx.x;
    const float2 c = coords[p];
    atomicAdd(&counts[bucket_of(c.x, c.y)], 1u);
}

__global__ __launch_bounds__(256) void scan_k(const unsigned* __restrict__ counts,
                                              unsigned* __restrict__ offsets) {
    __shared__ unsigned part[256];
    const int t = threadIdx.x;
    unsigned loc[16];
    unsigned sum = 0;
    #pragma unroll
    for (int k = 0; k < 16; ++k) {
        const unsigned c = counts[t * 16 + k];
        loc[k] = sum;
        sum += c;
    }
    part[t] = sum;
    __syncthreads();
    for (int off = 1; off < 256; off <<= 1) {
        const unsigned v = (t >= off) ? part[t - off] : 0u;
        __syncthreads();
        part[t] += v;
        __syncthreads();
    }
    const unsigned base = (t > 0) ? part[t - 1] : 0u;
    #pragma unroll
    for (int k = 0; k < 16; ++k)
        offsets[t * 16 + k] = base + loc[k];
}

__global__ __launch_bounds__(256) void scatter_k(const float2* __restrict__ coords,
                                                 unsigned* __restrict__ offsets,
                                                 float2* __restrict__ sxy,
                                                 unsigned* __restrict__ sidx) {
    const int p = blockIdx.x * blockDim.x + threadIdx.x;
    const float2 c = coords[p];
    const unsigned b = bucket_of(c.x, c.y);
    const unsigned pos = atomicAdd(&offsets[b], 1u);
    sxy[pos] = c;
    sidx[pos] = (unsigned)p;
}

__global__ __launch_bounds__(256) void ngp_fused(
    const float2* __restrict__ pts,      // sorted (or raw) coords
    const unsigned* __restrict__ sidx,   // original index, or nullptr
    const float* __restrict__ hashf,
    const float* __restrict__ W0,
    const float* __restrict__ b0,
    const float* __restrict__ W1,
    const float* __restrict__ b1,
    const float* __restrict__ W2,
    const float* __restrict__ b2,
    float* __restrict__ out,
    ResArr res)
{
    // XCD-chunked swizzle: 4096 blocks -> each XCD gets a contiguous Morton range
    const unsigned nwg = gridDim.x;
    const unsigned chunk = nwg >> 3;                     // nwg divisible by 8
    const unsigned sb = (blockIdx.x & 7u) * chunk + (blockIdx.x >> 3);
    const int p = (int)(sb * blockDim.x + threadIdx.x);

    const float2 c = pts[p];
    const unsigned oid = sidx ? sidx[p] : (unsigned)p;

    float f[2 * R_LEVELS];

    #pragma unroll
    for (int r = 0; r < R_LEVELS; ++r) {
        const float rr = res.r[r];
        const float x = c.x * rr;
        const float y = c.y * rr;
        const float xf = floorf(x);
        const float yf = floorf(y);
        const float wx = x - xf;
        const float wy = y - yf;
        const unsigned x0 = (unsigned)xf;
        const unsigned y0 = (unsigned)yf;
        const unsigned hy0 = PRIME_H * y0;
        const unsigned hy1 = PRIME_H * (y0 + 1u);
        const unsigned i00 = (x0 ^ hy0) & N_MASK;
        const unsigned i01 = (x0 ^ hy1) & N_MASK;
        const unsigned i10 = ((x0 + 1u) ^ hy0) & N_MASK;
        const unsigned i11 = ((x0 + 1u) ^ hy1) & N_MASK;
        const float2* tab = (const float2*)hashf + (size_t)r * N_TAB;
        const float2 v00 = tab[i00];
        const float2 v01 = tab[i01];
        const float2 v10 = tab[i10];
        const float2 v11 = tab[i11];
        const float w00 = (1.f - wx) * (1.f - wy);
        const float w01 = (1.f - wx) * wy;
        const float w10 = wx * (1.f - wy);
        const float w11 = wx * wy;
        f[2*r+0] = v00.x*w00 + v01.x*w01 + v10.x*w10 + v11.x*w11;
        f[2*r+1] = v00.y*w00 + v01.y*w01 + v10.y*w10 + v11.y*w11;
    }

    // ---- layer 0 ----
    float h0[H_DIM];
    #pragma unroll
    for (int j = 0; j < H_DIM; ++j) h0[j] = b0[j];
    #pragma unroll
    for (int i = 0; i < H_DIM; ++i) {
        const float fi = f[i];
        #pragma unroll
        for (int j = 0; j < H_DIM; ++j)
            h0[j] = fmaf(fi, W0[i*H_DIM + j], h0[j]);
    }
    #pragma unroll
    for (int j = 0; j < H_DIM; ++j) h0[j] = fmaxf(h0[j], 0.01f * h0[j]);

    // ---- layer 1 (reuse f[] as h1) ----
    #pragma unroll
    for (int j = 0; j < H_DIM; ++j) f[j] = b1[j];
    #pragma unroll
    for (int i = 0; i < H_DIM; ++i) {
        const float hi = h0[i];
        #pragma unroll
        for (int j = 0; j < H_DIM; ++j)
            f[j] = fmaf(hi, W1[i*H_DIM + j], f[j]);
    }
    #pragma unroll
    for (int j = 0; j < H_DIM; ++j) f[j] = fmaxf(f[j], 0.01f * f[j]);

    // ---- layer 2 ----
    float o0 = b2[0], o1 = b2[1], o2 = b2[2];
    #pragma unroll
    for (int i = 0; i < H_DIM; ++i) {
        const float hi = f[i];
        o0 = fmaf(hi, W2[i*3 + 0], o0);
        o1 = fmaf(hi, W2[i*3 + 1], o1);
        o2 = fmaf(hi, W2[i*3 + 2], o2);
    }

    out[(size_t)oid*3 + 0] = o0;
    out[(size_t)oid*3 + 1] = o1;
    out[(size_t)oid*3 + 2] = o2;
}

extern "C" void kernel_launch(void* const* d_in, const int* in_sizes, int n_in,
                              void* d_out, int out_size, void* d_ws, size_t ws_size,
                              hipStream_t stream) {
    ResArr res;
    for (int i = 0; i < R_LEVELS; ++i)
        res.r[i] = (float)nearbyint(exp2(4.0 + (7.0 / 15.0) * (double)i));
    res.r[0] = 16.f;
    res.r[R_LEVELS - 1] = 2048.f;

    const float2* coords = (const float2*)d_in[0];
    const float* hashf   = (const float*)d_in[1];
    const float* W0      = (const float*)d_in[2];
    const float* b0      = (const float*)d_in[3];
    const float* W1      = (const float*)d_in[4];
    const float* b1      = (const float*)d_in[5];
    const float* W2      = (const float*)d_in[6];
    const float* b2      = (const float*)d_in[7];
    float* out           = (float*)d_out;

    // ws layout: counts[4096] | offsets[4096] | sxy[M] (float2) | sidx[M] (u32)
    const size_t off_counts  = 0;
    const size_t off_offsets = 16384;
    const size_t off_sxy     = 32768;
    const size_t off_sidx    = off_sxy + (size_t)M_PTS * sizeof(float2);
    const size_t need        = off_sidx + (size_t)M_PTS * sizeof(unsigned);

    dim3 block(256);
    dim3 gridM(M_PTS / 256);

    if (ws_size >= need) {
        unsigned* counts  = (unsigned*)((char*)d_ws + off_counts);
        unsigned* offsets = (unsigned*)((char*)d_ws + off_offsets);
        float2*   sxy     = (float2*)((char*)d_ws + off_sxy);
        unsigned* sidx    = (unsigned*)((char*)d_ws + off_sidx);

        hipMemsetAsync(counts, 0, 16384, stream);
        hipLaunchKernelGGL(hist_k, gridM, block, 0, stream, coords, counts);
        hipLaunchKernelGGL(scan_k, dim3(1), block, 0, stream, counts, offsets);
        hipLaunchKernelGGL(scatter_k, gridM, block, 0, stream, coords, offsets, sxy, sidx);
        hipLaunchKernelGGL(ngp_fused, gridM, block, 0, stream,
                           sxy, sidx, hashf, W0, b0, W1, b1, W2, b2, out, res);
    } else {
        hipLaunchKernelGGL(ngp_fused, gridM, block, 0, stream,
                           coords, (const unsigned*)nullptr, hashf,
                           W0, b0, W1, b1, W2, b2, out, res);
    }
}

// Round 3
// 152.406 us; speedup vs baseline: 1.7000x; 1.7000x over previous
//
#include <hip/hip_runtime.h>
#include <cmath>

#define R_LEVELS 16
#define N_TAB    524288u
#define N_MASK   (N_TAB - 1u)
#define PRIME_H  2654435761u
#define H_DIM    32
#define M_PTS    1048576
#define BDIM     64               // buckets per axis
#define NBUCK    (BDIM * BDIM)    // 4096 Morton buckets
#define SBLK     64               // sort blocks
#define STHR     1024             // threads per sort block
#define SPB      (M_PTS / SBLK)   // 16384 points per sort block
#define SITER    (SPB / STHR)     // 16 points per thread

struct ResArr { float r[R_LEVELS]; };

__device__ __forceinline__ unsigned bucket_of(float x, float y) {
    unsigned bx = (unsigned)(x * (float)BDIM); if (bx >= BDIM) bx = BDIM - 1;
    unsigned by = (unsigned)(y * (float)BDIM); if (by >= BDIM) by = BDIM - 1;
    unsigned m = 0;
    #pragma unroll
    for (int i = 0; i < 6; ++i)
        m |= (((bx >> i) & 1u) << (2 * i)) | (((by >> i) & 1u) << (2 * i + 1));
    return m;
}

// Pass 1: per-block LDS histogram -> C[block][bucket] (plain stores)
__global__ __launch_bounds__(STHR) void hist_k(const float2* __restrict__ coords,
                                               unsigned* __restrict__ C) {
    __shared__ unsigned h[NBUCK];
    const int t = threadIdx.x;
    const int w = blockIdx.x;
    #pragma unroll
    for (int i = t; i < NBUCK; i += STHR) h[i] = 0u;
    __syncthreads();
    #pragma unroll
    for (int k = 0; k < SITER; ++k) {
        const int p = w * SPB + k * STHR + t;
        const float2 c = coords[p];
        atomicAdd(&h[bucket_of(c.x, c.y)], 1u);   // LDS atomic
    }
    __syncthreads();
    #pragma unroll
    for (int i = t; i < NBUCK; i += STHR) C[(size_t)w * NBUCK + i] = h[i];
}

// Pass 2a: exclusive prefix across blocks per bucket; totals -> T[bucket]
__global__ __launch_bounds__(256) void scanw_k(unsigned* __restrict__ C,
                                               unsigned* __restrict__ T) {
    const int b = blockIdx.x * 256 + threadIdx.x;   // 4096 threads total
    unsigned s = 0;
    for (int w = 0; w < SBLK; ++w) {
        const size_t i = (size_t)w * NBUCK + b;
        const unsigned v = C[i];
        C[i] = s;
        s += v;
    }
    T[b] = s;
}

// Pass 2b: exclusive prefix over T[4096] -> B[4096]
__global__ __launch_bounds__(256) void scan_k(const unsigned* __restrict__ T,
                                              unsigned* __restrict__ B) {
    __shared__ unsigned part[256];
    const int t = threadIdx.x;
    unsigned loc[16];
    unsigned sum = 0;
    #pragma unroll
    for (int k = 0; k < 16; ++k) {
        const unsigned c = T[t * 16 + k];
        loc[k] = sum;
        sum += c;
    }
    part[t] = sum;
    __syncthreads();
    for (int off = 1; off < 256; off <<= 1) {
        const unsigned v = (t >= off) ? part[t - off] : 0u;
        __syncthreads();
        part[t] += v;
        __syncthreads();
    }
    const unsigned base = (t > 0) ? part[t - 1] : 0u;
    #pragma unroll
    for (int k = 0; k < 16; ++k)
        B[t * 16 + k] = base + loc[k];
}

// Pass 3: scatter using LDS-resident per-bucket cursors (LDS atomics only)
__global__ __launch_bounds__(STHR) void scatter_k(const float2* __restrict__ coords,
                                                  const unsigned* __restrict__ C,
                                                  const unsigned* __restrict__ B,
                                                  float2* __restrict__ sxy,
                                                  unsigned* __restrict__ sidx) {
    __shared__ unsigned off[NBUCK];
    const int t = threadIdx.x;
    const int w = blockIdx.x;
    #pragma unroll
    for (int i = t; i < NBUCK; i += STHR)
        off[i] = B[i] + C[(size_t)w * NBUCK + i];
    __syncthreads();
    #pragma unroll
    for (int k = 0; k < SITER; ++k) {
        const int p = w * SPB + k * STHR + t;
        const float2 c = coords[p];
        const unsigned b = bucket_of(c.x, c.y);
        const unsigned pos = atomicAdd(&off[b], 1u);  // LDS atomic
        sxy[pos] = c;
        sidx[pos] = (unsigned)p;
    }
}

__global__ __launch_bounds__(256) void ngp_fused(
    const float2* __restrict__ pts,
    const unsigned* __restrict__ sidx,
    const float* __restrict__ hashf,
    const float* __restrict__ W0,
    const float* __restrict__ b0,
    const float* __restrict__ W1,
    const float* __restrict__ b1,
    const float* __restrict__ W2,
    const float* __restrict__ b2,
    float* __restrict__ out,
    ResArr res)
{
    const unsigned nwg = gridDim.x;
    const unsigned chunk = nwg >> 3;
    const unsigned sb = (blockIdx.x & 7u) * chunk + (blockIdx.x >> 3);
    const int p = (int)(sb * blockDim.x + threadIdx.x);

    const float2 c = pts[p];
    const unsigned oid = sidx ? sidx[p] : (unsigned)p;

    float f[2 * R_LEVELS];

    #pragma unroll
    for (int r = 0; r < R_LEVELS; ++r) {
        const float rr = res.r[r];
        const float x = c.x * rr;
        const float y = c.y * rr;
        const float xf = floorf(x);
        const float yf = floorf(y);
        const float wx = x - xf;
        const float wy = y - yf;
        const unsigned x0 = (unsigned)xf;
        const unsigned y0 = (unsigned)yf;
        const unsigned hy0 = PRIME_H * y0;
        const unsigned hy1 = PRIME_H * (y0 + 1u);
        const unsigned i00 = (x0 ^ hy0) & N_MASK;
        const unsigned i01 = (x0 ^ hy1) & N_MASK;
        const unsigned i10 = ((x0 + 1u) ^ hy0) & N_MASK;
        const unsigned i11 = ((x0 + 1u) ^ hy1) & N_MASK;
        const float2* tab = (const float2*)hashf + (size_t)r * N_TAB;
        const float2 v00 = tab[i00];
        const float2 v01 = tab[i01];
        const float2 v10 = tab[i10];
        const float2 v11 = tab[i11];
        const float w00 = (1.f - wx) * (1.f - wy);
        const float w01 = (1.f - wx) * wy;
        const float w10 = wx * (1.f - wy);
        const float w11 = wx * wy;
        f[2*r+0] = v00.x*w00 + v01.x*w01 + v10.x*w10 + v11.x*w11;
        f[2*r+1] = v00.y*w00 + v01.y*w01 + v10.y*w10 + v11.y*w11;
    }

    float h0[H_DIM];
    #pragma unroll
    for (int j = 0; j < H_DIM; ++j) h0[j] = b0[j];
    #pragma unroll
    for (int i = 0; i < H_DIM; ++i) {
        const float fi = f[i];
        #pragma unroll
        for (int j = 0; j < H_DIM; ++j)
            h0[j] = fmaf(fi, W0[i*H_DIM + j], h0[j]);
    }
    #pragma unroll
    for (int j = 0; j < H_DIM; ++j) h0[j] = fmaxf(h0[j], 0.01f * h0[j]);

    #pragma unroll
    for (int j = 0; j < H_DIM; ++j) f[j] = b1[j];
    #pragma unroll
    for (int i = 0; i < H_DIM; ++i) {
        const float hi = h0[i];
        #pragma unroll
        for (int j = 0; j < H_DIM; ++j)
            f[j] = fmaf(hi, W1[i*H_DIM + j], f[j]);
    }
    #pragma unroll
    for (int j = 0; j < H_DIM; ++j) f[j] = fmaxf(f[j], 0.01f * f[j]);

    float o0 = b2[0], o1 = b2[1], o2 = b2[2];
    #pragma unroll
    for (int i = 0; i < H_DIM; ++i) {
        const float hi = f[i];
        o0 = fmaf(hi, W2[i*3 + 0], o0);
        o1 = fmaf(hi, W2[i*3 + 1], o1);
        o2 = fmaf(hi, W2[i*3 + 2], o2);
    }

    out[(size_t)oid*3 + 0] = o0;
    out[(size_t)oid*3 + 1] = o1;
    out[(size_t)oid*3 + 2] = o2;
}

extern "C" void kernel_launch(void* const* d_in, const int* in_sizes, int n_in,
                              void* d_out, int out_size, void* d_ws, size_t ws_size,
                              hipStream_t stream) {
    ResArr res;
    for (int i = 0; i < R_LEVELS; ++i)
        res.r[i] = (float)nearbyint(exp2(4.0 + (7.0 / 15.0) * (double)i));
    res.r[0] = 16.f;
    res.r[R_LEVELS - 1] = 2048.f;

    const float2* coords = (const float2*)d_in[0];
    const float* hashf   = (const float*)d_in[1];
    const float* W0      = (const float*)d_in[2];
    const float* b0      = (const float*)d_in[3];
    const float* W1      = (const float*)d_in[4];
    const float* b1      = (const float*)d_in[5];
    const float* W2      = (const float*)d_in[6];
    const float* b2      = (const float*)d_in[7];
    float* out           = (float*)d_out;

    // ws layout: C[64*4096] | T[4096] | B[4096] | sxy[M] float2 | sidx[M] u32
    const size_t off_C    = 0;
    const size_t off_T    = off_C + (size_t)SBLK * NBUCK * 4;       // 1 MB
    const size_t off_B    = off_T + NBUCK * 4;
    const size_t off_sxy  = off_B + NBUCK * 4;
    const size_t off_sidx = off_sxy + (size_t)M_PTS * sizeof(float2);
    const size_t need     = off_sidx + (size_t)M_PTS * sizeof(unsigned);

    dim3 blockM(256);
    dim3 gridM(M_PTS / 256);

    if (ws_size >= need) {
        unsigned* C    = (unsigned*)((char*)d_ws + off_C);
        unsigned* T    = (unsigned*)((char*)d_ws + off_T);
        unsigned* B    = (unsigned*)((char*)d_ws + off_B);
        float2*   sxy  = (float2*)((char*)d_ws + off_sxy);
        unsigned* sidx = (unsigned*)((char*)d_ws + off_sidx);

        hipLaunchKernelGGL(hist_k,    dim3(SBLK), dim3(STHR), 0, stream, coords, C);
        hipLaunchKernelGGL(scanw_k,   dim3(NBUCK / 256), dim3(256), 0, stream, C, T);
        hipLaunchKernelGGL(scan_k,    dim3(1), dim3(256), 0, stream, T, B);
        hipLaunchKernelGGL(scatter_k, dim3(SBLK), dim3(STHR), 0, stream, coords, C, B, sxy, sidx);
        hipLaunchKernelGGL(ngp_fused, gridM, blockM, 0, stream,
                           sxy, sidx, hashf, W0, b0, W1, b1, W2, b2, out, res);
    } else {
        hipLaunchKernelGGL(ngp_fused, gridM, blockM, 0, stream,
                           coords, (const unsigned*)nullptr, hashf,
                           W0, b0, W1, b1, W2, b2, out, res);
    }
}

// Round 4
// 125.610 us; speedup vs baseline: 2.0626x; 1.2133x over previous
//
#include <hip/hip_runtime.h>
#include <cmath>

#define R_LEVELS 16
#define N_TAB    524288u
#define N_MASK   (N_TAB - 1u)
#define PRIME_H  2654435761u
#define M_PTS    1048576
#define BDIM     64
#define NBUCK    (BDIM * BDIM)
#define SBLK     64
#define STHR     1024
#define SPB      (M_PTS / SBLK)
#define SITER    (SPB / STHR)
#define XSTRIDE  36               // ushorts per LDS row: 32 ch + 4 pad (72 B)

typedef __attribute__((ext_vector_type(8)))  short bf16x8;
typedef __attribute__((ext_vector_type(16))) float f32x16;

union FragU { bf16x8 v; unsigned u[4]; uint2 u2[2]; };

struct ResArr { float r[R_LEVELS]; };

// pack_hi(f0,f1): u32 = [f0.top16 | f1.top16<<16]  (bf16 by truncation)
__device__ __forceinline__ unsigned pack_hi(float f0, float f1) {
    return __builtin_amdgcn_perm(__float_as_uint(f1), __float_as_uint(f0), 0x07060302u);
}
// pack_lo(f0,f1): bf16(residuals) packed, RTN via v_cvt_pk_bf16_f32
__device__ __forceinline__ unsigned pack_lo(float f0, float f1) {
    const float l0 = f0 - __uint_as_float(__float_as_uint(f0) & 0xffff0000u);
    const float l1 = f1 - __uint_as_float(__float_as_uint(f1) & 0xffff0000u);
    unsigned r;
    asm("v_cvt_pk_bf16_f32 %0, %1, %2" : "=v"(r) : "v"(l0), "v"(l1));
    return r;
}

__device__ __forceinline__ unsigned bucket_of(float x, float y) {
    unsigned bx = (unsigned)(x * (float)BDIM); if (bx >= BDIM) bx = BDIM - 1;
    unsigned by = (unsigned)(y * (float)BDIM); if (by >= BDIM) by = BDIM - 1;
    unsigned m = 0;
    #pragma unroll
    for (int i = 0; i < 6; ++i)
        m |= (((bx >> i) & 1u) << (2 * i)) | (((by >> i) & 1u) << (2 * i + 1));
    return m;
}

__global__ __launch_bounds__(STHR) void hist_k(const float2* __restrict__ coords,
                                               unsigned* __restrict__ C) {
    __shared__ unsigned h[NBUCK];
    const int t = threadIdx.x;
    const int w = blockIdx.x;
    #pragma unroll
    for (int i = t; i < NBUCK; i += STHR) h[i] = 0u;
    __syncthreads();
    #pragma unroll
    for (int k = 0; k < SITER; ++k) {
        const int p = w * SPB + k * STHR + t;
        const float2 c = coords[p];
        atomicAdd(&h[bucket_of(c.x, c.y)], 1u);
    }
    __syncthreads();
    #pragma unroll
    for (int i = t; i < NBUCK; i += STHR) C[(size_t)w * NBUCK + i] = h[i];
}

__global__ __launch_bounds__(256) void scanw_k(unsigned* __restrict__ C,
                                               unsigned* __restrict__ T) {
    const int b = blockIdx.x * 256 + threadIdx.x;
    unsigned s = 0;
    for (int w = 0; w < SBLK; ++w) {
        const size_t i = (size_t)w * NBUCK + b;
        const unsigned v = C[i];
        C[i] = s;
        s += v;
    }
    T[b] = s;
}

__global__ __launch_bounds__(256) void scan_k(const unsigned* __restrict__ T,
                                              unsigned* __restrict__ B) {
    __shared__ unsigned part[256];
    const int t = threadIdx.x;
    unsigned loc[16];
    unsigned sum = 0;
    #pragma unroll
    for (int k = 0; k < 16; ++k) {
        const unsigned c = T[t * 16 + k];
        loc[k] = sum;
        sum += c;
    }
    part[t] = sum;
    __syncthreads();
    for (int off = 1; off < 256; off <<= 1) {
        const unsigned v = (t >= off) ? part[t - off] : 0u;
        __syncthreads();
        part[t] += v;
        __syncthreads();
    }
    const unsigned base = (t > 0) ? part[t - 1] : 0u;
    #pragma unroll
    for (int k = 0; k < 16; ++k)
        B[t * 16 + k] = base + loc[k];
}

__global__ __launch_bounds__(STHR) void scatter_k(const float2* __restrict__ coords,
                                                  const unsigned* __restrict__ C,
                                                  const unsigned* __restrict__ B,
                                                  float2* __restrict__ sxy,
                                                  unsigned* __restrict__ sidx) {
    __shared__ unsigned off[NBUCK];
    const int t = threadIdx.x;
    const int w = blockIdx.x;
    #pragma unroll
    for (int i = t; i < NBUCK; i += STHR)
        off[i] = B[i] + C[(size_t)w * NBUCK + i];
    __syncthreads();
    #pragma unroll
    for (int k = 0; k < SITER; ++k) {
        const int p = w * SPB + k * STHR + t;
        const float2 c = coords[p];
        const unsigned b = bucket_of(c.x, c.y);
        const unsigned pos = atomicAdd(&off[b], 1u);
        sxy[pos] = c;
        sidx[pos] = (unsigned)p;
    }
}

__global__ __launch_bounds__(256) void ngp_mfma(
    const float2* __restrict__ pts,
    const unsigned* __restrict__ sidx,
    const float* __restrict__ hashf,
    const float* __restrict__ W0, const float* __restrict__ b0,
    const float* __restrict__ W1, const float* __restrict__ b1,
    const float* __restrict__ W2, const float* __restrict__ b2,
    float* __restrict__ out, ResArr res)
{
    // per-wave-private slices: wave w owns rows [w*64, w*64+64) -> NO barriers
    __shared__ unsigned short Xh[256 * XSTRIDE];
    __shared__ unsigned short Xl[256 * XSTRIDE];

    const unsigned nwg = gridDim.x;
    const unsigned chunk = nwg >> 3;
    const unsigned sb = (blockIdx.x & 7u) * chunk + (blockIdx.x >> 3);
    const int tid = threadIdx.x;
    const int pb = (int)(sb * 256u);

    const float2 c = pts[pb + tid];

    // ---- hash-grid bilinear interp: f[32] fp32 ----
    float f[32];
    #pragma unroll
    for (int r = 0; r < R_LEVELS; ++r) {
        const float rr = res.r[r];
        const float x = c.x * rr;
        const float y = c.y * rr;
        const float xf = floorf(x);
        const float yf = floorf(y);
        const float wx = x - xf;
        const float wy = y - yf;
        const unsigned x0 = (unsigned)xf;
        const unsigned y0 = (unsigned)yf;
        const unsigned hy0 = PRIME_H * y0;
        const unsigned hy1 = PRIME_H * (y0 + 1u);
        const unsigned i00 = (x0 ^ hy0) & N_MASK;
        const unsigned i01 = (x0 ^ hy1) & N_MASK;
        const unsigned i10 = ((x0 + 1u) ^ hy0) & N_MASK;
        const unsigned i11 = ((x0 + 1u) ^ hy1) & N_MASK;
        const float2* tab = (const float2*)hashf + (size_t)r * N_TAB;
        const float2 v00 = tab[i00];
        const float2 v01 = tab[i01];
        const float2 v10 = tab[i10];
        const float2 v11 = tab[i11];
        const float w00 = (1.f - wx) * (1.f - wy);
        const float w01 = (1.f - wx) * wy;
        const float w10 = wx * (1.f - wy);
        const float w11 = wx * wy;
        f[2*r+0] = v00.x*w00 + v01.x*w01 + v10.x*w10 + v11.x*w11;
        f[2*r+1] = v00.y*w00 + v01.y*w01 + v10.y*w10 + v11.y*w11;
    }

    // ---- split f -> bf16 hi/lo, stage LDS row [tid][ch] ----
    {
        const int rowo = tid * XSTRIDE;
        #pragma unroll
        for (int q = 0; q < 8; ++q) {
            uint2 ph, pl;
            ph.x = pack_hi(f[4*q+0], f[4*q+1]);
            ph.y = pack_hi(f[4*q+2], f[4*q+3]);
            pl.x = pack_lo(f[4*q+0], f[4*q+1]);
            pl.y = pack_lo(f[4*q+2], f[4*q+3]);
            *(uint2*)&Xh[rowo + 4*q] = ph;
            *(uint2*)&Xl[rowo + 4*q] = pl;
        }
    }

    const int lane = tid & 63;
    const int wv   = tid >> 6;
    const int l31  = lane & 31;
    const int h    = lane >> 5;
    const int tb0  = wv * 64;
    const int tb1  = wv * 64 + 32;

    // B-fragment: lane reads chs {kc*16+h*4+0..3, kc*16+8+h*4+0..3} of pt row
    auto ldx = [&](const unsigned short* X, int ptl, int kc) -> bf16x8 {
        FragU r;
        const int off = ptl * XSTRIDE + kc * 16 + h * 4;
        r.u2[0] = *(const uint2*)&X[off];
        r.u2[1] = *(const uint2*)&X[off + 8];
        return r.v;
    };

    // A-fragment from W[k][col] (col = out channel = l31), zero-padded if col>=ncol
    auto wfrag = [&](const float* W, int ncol, int kc, bf16x8& fh, bf16x8& fl) {
        float wv8[8];
        #pragma unroll
        for (int e = 0; e < 8; ++e) {
            const int k = kc*16 + (e>>2)*8 + h*4 + (e&3);
            wv8[e] = (l31 < ncol) ? W[k*ncol + l31] : 0.f;
        }
        FragU H, L;
        #pragma unroll
        for (int w = 0; w < 4; ++w) {
            H.u[w] = pack_hi(wv8[2*w], wv8[2*w+1]);
            L.u[w] = pack_lo(wv8[2*w], wv8[2*w+1]);
        }
        fh = H.v; fl = L.v;
    };

    // C/D row for reg r: (r&3) + 8*(r>>2) + 4*h   [measured m74/m101]
    auto bias16 = [&](const float* b, int nvalid) -> f32x16 {
        f32x16 a;
        #pragma unroll
        for (int r = 0; r < 16; ++r) {
            const int rw = (r&3) + 8*(r>>2) + 4*h;
            a[r] = (rw < nvalid) ? b[rw] : 0.f;
        }
        return a;
    };

    auto layer = [&](const float* W, const float* b, int ncol, f32x16& a0, f32x16& a1) {
        a0 = bias16(b, ncol);
        a1 = bias16(b, ncol);
        #pragma unroll
        for (int kc = 0; kc < 2; ++kc) {
            bf16x8 wh, wl;
            wfrag(W, ncol, kc, wh, wl);
            {
                bf16x8 xh = ldx(Xh, tb0 + l31, kc);
                bf16x8 xl = ldx(Xl, tb0 + l31, kc);
                a0 = __builtin_amdgcn_mfma_f32_32x32x16_bf16(wh, xh, a0, 0, 0, 0);
                a0 = __builtin_amdgcn_mfma_f32_32x32x16_bf16(wh, xl, a0, 0, 0, 0);
                a0 = __builtin_amdgcn_mfma_f32_32x32x16_bf16(wl, xh, a0, 0, 0, 0);
            }
            {
                bf16x8 yh = ldx(Xh, tb1 + l31, kc);
                bf16x8 yl = ldx(Xl, tb1 + l31, kc);
                a1 = __builtin_amdgcn_mfma_f32_32x32x16_bf16(wh, yh, a1, 0, 0, 0);
                a1 = __builtin_amdgcn_mfma_f32_32x32x16_bf16(wh, yl, a1, 0, 0, 0);
                a1 = __builtin_amdgcn_mfma_f32_32x32x16_bf16(wl, yh, a1, 0, 0, 0);
            }
        }
    };

    // leaky + split + write activations back to LDS (regs 4q..4q+3 -> chs 8q+4h..+3)
    auto store_act = [&](const f32x16& a, int ptl) {
        const int rowo = ptl * XSTRIDE;
        #pragma unroll
        for (int q = 0; q < 4; ++q) {
            float v0 = a[4*q+0], v1 = a[4*q+1], v2 = a[4*q+2], v3 = a[4*q+3];
            v0 = fmaxf(v0, 0.01f*v0);
            v1 = fmaxf(v1, 0.01f*v1);
            v2 = fmaxf(v2, 0.01f*v2);
            v3 = fmaxf(v3, 0.01f*v3);
            uint2 ph, pl;
            ph.x = pack_hi(v0, v1); ph.y = pack_hi(v2, v3);
            pl.x = pack_lo(v0, v1); pl.y = pack_lo(v2, v3);
            const int off = rowo + 8*q + 4*h;
            *(uint2*)&Xh[off] = ph;
            *(uint2*)&Xl[off] = pl;
        }
    };

    f32x16 a0, a1;
    layer(W0, b0, 32, a0, a1);
    store_act(a0, tb0 + l31);
    store_act(a1, tb1 + l31);
    layer(W1, b1, 32, a0, a1);
    store_act(a0, tb0 + l31);
    store_act(a1, tb1 + l31);
    layer(W2, b2, 3, a0, a1);

    if (h == 0) {
        const int pg0 = pb + tb0 + l31;
        const int pg1 = pb + tb1 + l31;
        const unsigned o0 = sidx ? sidx[pg0] : (unsigned)pg0;
        const unsigned o1 = sidx ? sidx[pg1] : (unsigned)pg1;
        out[(size_t)o0*3 + 0] = a0[0];
        out[(size_t)o0*3 + 1] = a0[1];
        out[(size_t)o0*3 + 2] = a0[2];
        out[(size_t)o1*3 + 0] = a1[0];
        out[(size_t)o1*3 + 1] = a1[1];
        out[(size_t)o1*3 + 2] = a1[2];
    }
}

extern "C" void kernel_launch(void* const* d_in, const int* in_sizes, int n_in,
                              void* d_out, int out_size, void* d_ws, size_t ws_size,
                              hipStream_t stream) {
    ResArr res;
    for (int i = 0; i < R_LEVELS; ++i)
        res.r[i] = (float)nearbyint(exp2(4.0 + (7.0 / 15.0) * (double)i));
    res.r[0] = 16.f;
    res.r[R_LEVELS - 1] = 2048.f;

    const float2* coords = (const float2*)d_in[0];
    const float* hashf   = (const float*)d_in[1];
    const float* W0      = (const float*)d_in[2];
    const float* b0      = (const float*)d_in[3];
    const float* W1      = (const float*)d_in[4];
    const float* b1      = (const float*)d_in[5];
    const float* W2      = (const float*)d_in[6];
    const float* b2      = (const float*)d_in[7];
    float* out           = (float*)d_out;

    const size_t off_C    = 0;
    const size_t off_T    = off_C + (size_t)SBLK * NBUCK * 4;
    const size_t off_B    = off_T + NBUCK * 4;
    const size_t off_sxy  = off_B + NBUCK * 4;
    const size_t off_sidx = off_sxy + (size_t)M_PTS * sizeof(float2);
    const size_t need     = off_sidx + (size_t)M_PTS * sizeof(unsigned);

    dim3 blockM(256);
    dim3 gridM(M_PTS / 256);

    if (ws_size >= need) {
        unsigned* C    = (unsigned*)((char*)d_ws + off_C);
        unsigned* T    = (unsigned*)((char*)d_ws + off_T);
        unsigned* B    = (unsigned*)((char*)d_ws + off_B);
        float2*   sxy  = (float2*)((char*)d_ws + off_sxy);
        unsigned* sidx = (unsigned*)((char*)d_ws + off_sidx);

        hipLaunchKernelGGL(hist_k,    dim3(SBLK), dim3(STHR), 0, stream, coords, C);
        hipLaunchKernelGGL(scanw_k,   dim3(NBUCK / 256), dim3(256), 0, stream, C, T);
        hipLaunchKernelGGL(scan_k,    dim3(1), dim3(256), 0, stream, T, B);
        hipLaunchKernelGGL(scatter_k, dim3(SBLK), dim3(STHR), 0, stream, coords, C, B, sxy, sidx);
        hipLaunchKernelGGL(ngp_mfma,  gridM, blockM, 0, stream,
                           sxy, sidx, hashf, W0, b0, W1, b1, W2, b2, out, res);
    } else {
        hipLaunchKernelGGL(ngp_mfma,  gridM, blockM, 0, stream,
                           coords, (const unsigned*)nullptr, hashf,
                           W0, b0, W1, b1, W2, b2, out, res);
    }
}

// Round 6
// 123.325 us; speedup vs baseline: 2.1008x; 1.0185x over previous
//
#include <hip/hip_runtime.h>
#include <cmath>

#define R_LEVELS 16
#define N_TAB    524288u
#define N_MASK   (N_TAB - 1u)
#define PRIME_H  2654435761u
#define M_PTS    1048576
#define BDIM     128              // buckets per axis
#define NBUCK    (BDIM * BDIM)    // 16384 Morton buckets
#define SBLK     64               // sort blocks
#define STHR     1024
#define SPB      (M_PTS / SBLK)   // 16384 (fits u16)
#define SITER    (SPB / STHR)     // 16
#define XSTRIDE  36               // bf16 elems per LDS row: 32 ch + 4 pad (72 B)
#define NFRAG    384              // 6 (layer,kc) x 64 lanes

typedef __attribute__((ext_vector_type(8)))  short bf16x8;
typedef __attribute__((ext_vector_type(16))) float f32x16;

union FragU { bf16x8 v; uint4 q; unsigned u[4]; uint2 u2[2]; unsigned short s[8]; };

struct ResArr { float r[R_LEVELS]; };

// pack_hi(f0,f1): u32 = [f0.top16 | f1.top16<<16]  (bf16 by truncation)
__device__ __forceinline__ unsigned pack_hi(float f0, float f1) {
    return __builtin_amdgcn_perm(__float_as_uint(f1), __float_as_uint(f0), 0x07060302u);
}
// pack_lo(f0,f1): bf16(residuals) packed, RTN via v_cvt_pk_bf16_f32
__device__ __forceinline__ unsigned pack_lo(float f0, float f1) {
    const float l0 = f0 - __uint_as_float(__float_as_uint(f0) & 0xffff0000u);
    const float l1 = f1 - __uint_as_float(__float_as_uint(f1) & 0xffff0000u);
    unsigned r;
    asm("v_cvt_pk_bf16_f32 %0, %1, %2" : "=v"(r) : "v"(l0), "v"(l1));
    return r;
}

__device__ __forceinline__ unsigned bucket_of(float x, float y) {
    unsigned bx = (unsigned)(x * (float)BDIM); if (bx >= BDIM) bx = BDIM - 1;
    unsigned by = (unsigned)(y * (float)BDIM); if (by >= BDIM) by = BDIM - 1;
    unsigned m = 0;
    #pragma unroll
    for (int i = 0; i < 7; ++i)
        m |= (((bx >> i) & 1u) << (2 * i)) | (((by >> i) & 1u) << (2 * i + 1));
    return m;
}

// Pass 1: per-block LDS histogram -> C[block][bucket] (u16, plain stores)
__global__ __launch_bounds__(STHR) void hist_k(const float2* __restrict__ coords,
                                               unsigned short* __restrict__ C) {
    __shared__ unsigned h[NBUCK];
    const int t = threadIdx.x;
    const int w = blockIdx.x;
    #pragma unroll
    for (int i = t; i < NBUCK; i += STHR) h[i] = 0u;
    __syncthreads();
    #pragma unroll
    for (int k = 0; k < SITER; ++k) {
        const int p = w * SPB + k * STHR + t;
        const float2 c = coords[p];
        atomicAdd(&h[bucket_of(c.x, c.y)], 1u);
    }
    __syncthreads();
    #pragma unroll
    for (int i = t; i < NBUCK; i += STHR)
        C[(size_t)w * NBUCK + i] = (unsigned short)h[i];
}

// Pass 2a: exclusive prefix across blocks per bucket; totals -> T[bucket]
__global__ __launch_bounds__(256) void scanw_k(unsigned short* __restrict__ C,
                                               unsigned* __restrict__ T) {
    const int b = blockIdx.x * 256 + threadIdx.x;   // 16384 threads total
    unsigned s = 0;
    for (int w = 0; w < SBLK; ++w) {
        const size_t i = (size_t)w * NBUCK + b;
        const unsigned v = C[i];
        C[i] = (unsigned short)s;
        s += v;
    }
    T[b] = s;
}

// Pass 2b: exclusive prefix over T[16384] -> B (single block, 64/thread, 2-pass)
__global__ __launch_bounds__(256) void scan_k(const unsigned* __restrict__ T,
                                              unsigned* __restrict__ B) {
    __shared__ unsigned part[256];
    const int t = threadIdx.x;
    unsigned sum = 0;
    for (int k = 0; k < 64; ++k) sum += T[t * 64 + k];
    part[t] = sum;
    __syncthreads();
    for (int off = 1; off < 256; off <<= 1) {
        const unsigned v = (t >= off) ? part[t - off] : 0u;
        __syncthreads();
        part[t] += v;
        __syncthreads();
    }
    unsigned run = (t > 0) ? part[t - 1] : 0u;
    for (int k = 0; k < 64; ++k) {
        B[t * 64 + k] = run;
        run += T[t * 64 + k];
    }
}

// Pass 3: scatter permutation only (LDS cursors, LDS atomics)
__global__ __launch_bounds__(STHR) void scatter_k(const float2* __restrict__ coords,
                                                  const unsigned short* __restrict__ C,
                                                  const unsigned* __restrict__ B,
                                                  unsigned* __restrict__ sidx) {
    __shared__ unsigned off[NBUCK];
    const int t = threadIdx.x;
    const int w = blockIdx.x;
    #pragma unroll
    for (int i = t; i < NBUCK; i += STHR)
        off[i] = B[i] + (unsigned)C[(size_t)w * NBUCK + i];
    __syncthreads();
    #pragma unroll
    for (int k = 0; k < SITER; ++k) {
        const int p = w * SPB + k * STHR + t;
        const float2 c = coords[p];
        const unsigned b = bucket_of(c.x, c.y);
        const unsigned pos = atomicAdd(&off[b], 1u);
        sidx[pos] = (unsigned)p;
    }
}

// Precompute bf16 hi/lo weight fragments (lane-ready) + zero-padded b2.
__global__ __launch_bounds__(64) void wprep_k(const float* __restrict__ W0,
                                              const float* __restrict__ W1,
                                              const float* __restrict__ W2,
                                              const float* __restrict__ b2,
                                              uint4* __restrict__ wbuf,   // [hi:384][lo:384]
                                              float* __restrict__ b2p) {
    const int lane = threadIdx.x;
    const int l31 = lane & 31;
    const int h   = lane >> 5;
    const float* Ws[3] = {W0, W1, W2};
    const int ncols[3] = {32, 32, 3};
    for (int l = 0; l < 3; ++l) {
        for (int kc = 0; kc < 2; ++kc) {
            FragU H, L;
            for (int e = 0; e < 8; ++e) {
                const int k = kc*16 + (e>>2)*8 + h*4 + (e&3);
                const float w = (l31 < ncols[l]) ? Ws[l][k*ncols[l] + l31] : 0.f;
                const unsigned short hi = (unsigned short)(__float_as_uint(w) >> 16);
                const float rem = w - __uint_as_float((unsigned)hi << 16);
                const unsigned u = __float_as_uint(rem);
                const unsigned short lo = (unsigned short)((u + 0x7fffu + ((u >> 16) & 1u)) >> 16);
                H.s[e] = hi;
                L.s[e] = lo;
            }
            const int fi = (l*2 + kc)*64 + lane;
            wbuf[fi]         = H.q;
            wbuf[NFRAG + fi] = L.q;
        }
    }
    if (lane < 32) b2p[lane] = (lane < 3) ? b2[lane] : 0.f;
}

__global__ __launch_bounds__(256) void ngp_mfma(
    const float2* __restrict__ coords,
    const unsigned* __restrict__ sidx,   // permutation, or nullptr
    const float* __restrict__ hashf,
    const uint4* __restrict__ wbuf,
    const float* __restrict__ b0,
    const float* __restrict__ b1,
    const float* __restrict__ b2p,
    float* __restrict__ out, ResArr res)
{
    // wave-private row slices -> no barriers
    __shared__ unsigned short Xh[256 * XSTRIDE];
    __shared__ unsigned short Xl[256 * XSTRIDE];

    const unsigned nwg = gridDim.x;
    const unsigned chunk = nwg >> 3;
    const unsigned sb = (blockIdx.x & 7u) * chunk + (blockIdx.x >> 3);
    const int tid = threadIdx.x;
    const int p = (int)(sb * 256u) + tid;

    const unsigned oid = sidx ? sidx[p] : (unsigned)p;
    const float2 c = coords[oid];

    // ---- interp, 2 chunks of 8 levels (32 loads in flight per chunk) ----
    float f[32];
    #pragma unroll
    for (int ck = 0; ck < 2; ++ck) {
        float2 v00[8], v01[8], v10[8], v11[8];
        float wxs[8], wys[8];
        #pragma unroll
        for (int j = 0; j < 8; ++j) {
            const int r = ck * 8 + j;
            const float rr = res.r[r];
            const float x = c.x * rr;
            const float y = c.y * rr;
            const float xf = floorf(x);
            const float yf = floorf(y);
            wxs[j] = x - xf;
            wys[j] = y - yf;
            const unsigned x0 = (unsigned)xf;
            const unsigned y0 = (unsigned)yf;
            const unsigned hy0 = PRIME_H * y0;
            const unsigned hy1 = PRIME_H * (y0 + 1u);
            const unsigned i00 = (x0 ^ hy0) & N_MASK;
            const unsigned i01 = (x0 ^ hy1) & N_MASK;
            const unsigned i10 = ((x0 + 1u) ^ hy0) & N_MASK;
            const unsigned i11 = ((x0 + 1u) ^ hy1) & N_MASK;
            const float2* tab = (const float2*)hashf + (size_t)r * N_TAB;
            v00[j] = tab[i00];
            v01[j] = tab[i01];
            v10[j] = tab[i10];
            v11[j] = tab[i11];
        }
        #pragma unroll
        for (int j = 0; j < 8; ++j) {
            const float wx = wxs[j], wy = wys[j];
            const float w00 = (1.f - wx) * (1.f - wy);
            const float w01 = (1.f - wx) * wy;
            const float w10 = wx * (1.f - wy);
            const float w11 = wx * wy;
            const int r = ck * 8 + j;
            f[2*r+0] = v00[j].x*w00 + v01[j].x*w01 + v10[j].x*w10 + v11[j].x*w11;
            f[2*r+1] = v00[j].y*w00 + v01[j].y*w01 + v10[j].y*w10 + v11[j].y*w11;
        }
    }

    // ---- split f -> bf16 hi/lo, stage LDS row [tid][ch] ----
    {
        const int rowo = tid * XSTRIDE;
        #pragma unroll
        for (int q = 0; q < 8; ++q) {
            uint2 ph, pl;
            ph.x = pack_hi(f[4*q+0], f[4*q+1]);
            ph.y = pack_hi(f[4*q+2], f[4*q+3]);
            pl.x = pack_lo(f[4*q+0], f[4*q+1]);
            pl.y = pack_lo(f[4*q+2], f[4*q+3]);
            *(uint2*)&Xh[rowo + 4*q] = ph;
            *(uint2*)&Xl[rowo + 4*q] = pl;
        }
    }

    const int lane = tid & 63;
    const int wv   = tid >> 6;
    const int l31  = lane & 31;
    const int h    = lane >> 5;
    const int tb0  = wv * 64;
    const int tb1  = wv * 64 + 32;

    auto ldx = [&](const unsigned short* X, int ptl, int kc) -> bf16x8 {
        FragU r;
        const int off = ptl * XSTRIDE + kc * 16 + h * 4;
        r.u2[0] = *(const uint2*)&X[off];
        r.u2[1] = *(const uint2*)&X[off + 8];
        return r.v;
    };

    // a[4q+j] = b[8q + 4h + j]
    auto bias_init = [&](const float* b) -> f32x16 {
        f32x16 a;
        #pragma unroll
        for (int q = 0; q < 4; ++q) {
            const float4 t = *(const float4*)(b + 8*q + 4*h);
            a[4*q+0] = t.x; a[4*q+1] = t.y; a[4*q+2] = t.z; a[4*q+3] = t.w;
        }
        return a;
    };

    auto layer = [&](int l, const float* b, f32x16& a0, f32x16& a1) {
        FragU wh0, wl0, wh1, wl1;
        wh0.q = wbuf[(l*2+0)*64 + lane];
        wl0.q = wbuf[NFRAG + (l*2+0)*64 + lane];
        wh1.q = wbuf[(l*2+1)*64 + lane];
        wl1.q = wbuf[NFRAG + (l*2+1)*64 + lane];
        f32x16 A0 = bias_init(b);
        f32x16 A1 = A0;
        {
            const bf16x8 xh = ldx(Xh, tb0 + l31, 0);
            const bf16x8 xl = ldx(Xl, tb0 + l31, 0);
            A0 = __builtin_amdgcn_mfma_f32_32x32x16_bf16(wh0.v, xh, A0, 0, 0, 0);
            A0 = __builtin_amdgcn_mfma_f32_32x32x16_bf16(wh0.v, xl, A0, 0, 0, 0);
            A0 = __builtin_amdgcn_mfma_f32_32x32x16_bf16(wl0.v, xh, A0, 0, 0, 0);
        }
        {
            const bf16x8 xh = ldx(Xh, tb1 + l31, 0);
            const bf16x8 xl = ldx(Xl, tb1 + l31, 0);
            A1 = __builtin_amdgcn_mfma_f32_32x32x16_bf16(wh0.v, xh, A1, 0, 0, 0);
            A1 = __builtin_amdgcn_mfma_f32_32x32x16_bf16(wh0.v, xl, A1, 0, 0, 0);
            A1 = __builtin_amdgcn_mfma_f32_32x32x16_bf16(wl0.v, xh, A1, 0, 0, 0);
        }
        {
            const bf16x8 xh = ldx(Xh, tb0 + l31, 1);
            const bf16x8 xl = ldx(Xl, tb0 + l31, 1);
            A0 = __builtin_amdgcn_mfma_f32_32x32x16_bf16(wh1.v, xh, A0, 0, 0, 0);
            A0 = __builtin_amdgcn_mfma_f32_32x32x16_bf16(wh1.v, xl, A0, 0, 0, 0);
            A0 = __builtin_amdgcn_mfma_f32_32x32x16_bf16(wl1.v, xh, A0, 0, 0, 0);
        }
        {
            const bf16x8 xh = ldx(Xh, tb1 + l31, 1);
            const bf16x8 xl = ldx(Xl, tb1 + l31, 1);
            A1 = __builtin_amdgcn_mfma_f32_32x32x16_bf16(wh1.v, xh, A1, 0, 0, 0);
            A1 = __builtin_amdgcn_mfma_f32_32x32x16_bf16(wh1.v, xl, A1, 0, 0, 0);
            A1 = __builtin_amdgcn_mfma_f32_32x32x16_bf16(wl1.v, xh, A1, 0, 0, 0);
        }
        a0 = A0; a1 = A1;
    };

    // leaky + split + write activations back to LDS (reg 4q+j -> ch 8q+4h+j)
    auto store_act = [&](const f32x16& a, int ptl) {
        const int rowo = ptl * XSTRIDE;
        #pragma unroll
        for (int q = 0; q < 4; ++q) {
            float v0 = a[4*q+0], v1 = a[4*q+1], v2 = a[4*q+2], v3 = a[4*q+3];
            v0 = fmaxf(v0, 0.01f*v0);
            v1 = fmaxf(v1, 0.01f*v1);
            v2 = fmaxf(v2, 0.01f*v2);
            v3 = fmaxf(v3, 0.01f*v3);
            uint2 ph, pl;
            ph.x = pack_hi(v0, v1); ph.y = pack_hi(v2, v3);
            pl.x = pack_lo(v0, v1); pl.y = pack_lo(v2, v3);
            const int off = rowo + 8*q + 4*h;
            *(uint2*)&Xh[off] = ph;
            *(uint2*)&Xl[off] = pl;
        }
    };

    f32x16 a0, a1;
    layer(0, b0, a0, a1);
    store_act(a0, tb0 + l31);
    store_act(a1, tb1 + l31);
    layer(1, b1, a0, a1);
    store_act(a0, tb0 + l31);
    store_act(a1, tb1 + l31);
    layer(2, b2p, a0, a1);

    if (h == 0) {
        const int pl0 = (int)(sb * 256u) + tb0 + l31;
        const int pl1 = (int)(sb * 256u) + tb1 + l31;
        const unsigned o0 = sidx ? sidx[pl0] : (unsigned)pl0;
        const unsigned o1 = sidx ? sidx[pl1] : (unsigned)pl1;
        out[(size_t)o0*3 + 0] = a0[0];
        out[(size_t)o0*3 + 1] = a0[1];
        out[(size_t)o0*3 + 2] = a0[2];
        out[(size_t)o1*3 + 0] = a1[0];
        out[(size_t)o1*3 + 1] = a1[1];
        out[(size_t)o1*3 + 2] = a1[2];
    }
}

extern "C" void kernel_launch(void* const* d_in, const int* in_sizes, int n_in,
                              void* d_out, int out_size, void* d_ws, size_t ws_size,
                              hipStream_t stream) {
    ResArr res;
    for (int i = 0; i < R_LEVELS; ++i)
        res.r[i] = (float)nearbyint(exp2(4.0 + (7.0 / 15.0) * (double)i));
    res.r[0] = 16.f;
    res.r[R_LEVELS - 1] = 2048.f;

    const float2* coords = (const float2*)d_in[0];
    const float* hashf   = (const float*)d_in[1];
    const float* W0      = (const float*)d_in[2];
    const float* b0      = (const float*)d_in[3];
    const float* W1      = (const float*)d_in[4];
    const float* b1      = (const float*)d_in[5];
    const float* W2      = (const float*)d_in[6];
    const float* b2      = (const float*)d_in[7];
    float* out           = (float*)d_out;

    // ws: C u16[64*16384] | T u32[16384] | B u32[16384] | sidx u32[M] | wbuf | b2p
    const size_t off_C    = 0;
    const size_t off_T    = off_C + (size_t)SBLK * NBUCK * 2;       // 2 MB
    const size_t off_B    = off_T + NBUCK * 4;
    const size_t off_sidx = off_B + NBUCK * 4;
    const size_t off_wbuf = off_sidx + (size_t)M_PTS * 4;
    const size_t off_b2p  = off_wbuf + 2 * NFRAG * sizeof(uint4);
    const size_t need     = off_b2p + 32 * sizeof(float);
    const size_t need_min = 2 * NFRAG * sizeof(uint4) + 32 * sizeof(float);

    dim3 blockM(256);
    dim3 gridM(M_PTS / 256);

    if (ws_size >= need) {
        unsigned short* C = (unsigned short*)((char*)d_ws + off_C);
        unsigned* T    = (unsigned*)((char*)d_ws + off_T);
        unsigned* B    = (unsigned*)((char*)d_ws + off_B);
        unsigned* sidx = (unsigned*)((char*)d_ws + off_sidx);
        uint4*    wbuf = (uint4*)((char*)d_ws + off_wbuf);
        float*    b2p  = (float*)((char*)d_ws + off_b2p);

        hipLaunchKernelGGL(wprep_k,   dim3(1), dim3(64), 0, stream, W0, W1, W2, b2, wbuf, b2p);
        hipLaunchKernelGGL(hist_k,    dim3(SBLK), dim3(STHR), 0, stream, coords, C);
        hipLaunchKernelGGL(scanw_k,   dim3(NBUCK / 256), dim3(256), 0, stream, C, T);
        hipLaunchKernelGGL(scan_k,    dim3(1), dim3(256), 0, stream, T, B);
        hipLaunchKernelGGL(scatter_k, dim3(SBLK), dim3(STHR), 0, stream, coords, C, B, sidx);
        hipLaunchKernelGGL(ngp_mfma,  gridM, blockM, 0, stream,
                           coords, sidx, hashf, wbuf, b0, b1, b2p, out, res);
    } else if (ws_size >= need_min) {
        uint4* wbuf = (uint4*)d_ws;
        float* b2p  = (float*)((char*)d_ws + 2 * NFRAG * sizeof(uint4));
        hipLaunchKernelGGL(wprep_k,   dim3(1), dim3(64), 0, stream, W0, W1, W2, b2, wbuf, b2p);
        hipLaunchKernelGGL(ngp_mfma,  gridM, blockM, 0, stream,
                           coords, (const unsigned*)nullptr, hashf, wbuf, b0, b1, b2p, out, res);
    }
}